// Round 2
// baseline (383.914 us; speedup 1.0000x reference)
//
#include <hip/hip_runtime.h>

// RLGate, round 2: split fused kernel into gate+sample / combine / reduce.
// Round-1 failure mode: per-token blocks re-walked the 32KB W matrix with
// 32 scalar loads/thread at 128B thread stride -> every wave-level load hit
// 64 distinct cache lines (L1 serialization), 8192 blocks x 32KB. Fix:
// amortize W across 16 tokens/block via an LDS-transposed copy (coalesced
// global reads, conflict-free LDS access), and make the combine a pure
// stream kernel.
//
// NUMERICS: logits are computed with bitwise-identical FP order to the
// round-1 PASSING kernel (absmax 0.0): 4 separate per-"wave" accumulators
// with the same fmaf chain (j inner, e outer), same 64-lane xor butterfly,
// same S0+S1+S2+S3+bias order, same scalar softmax/Gumbel/top-2 code.
// So expert selections cannot flip vs round 1.

#define GATE_EPS 1e-9f

__global__ __launch_bounds__(256) void rlgate_gate(
    const float* __restrict__ x,        // [BT, D]
    const float* __restrict__ rewards,  // [BT]
    const float* __restrict__ W,        // [D, E]
    const float* __restrict__ bvec,     // [E]
    const float* __restrict__ baseline, // [1]
    const float* __restrict__ noise,    // [BT, E]
    int2*  __restrict__ idx_ws,         // [BT] selected expert pairs
    float* __restrict__ aux_ws,         // [BT] per-token aux terms
    int BT, int D)
{
    constexpr int E = 8;
    const int tid  = threadIdx.x;
    const int lane = tid & 63;
    const int wave = tid >> 6;

    // ---- stage W transposed into LDS: WT[e][d] = W[d][e] ----
    // Global: thread t reads rows t, t+256, t+512, t+768 (2 KB/wave/instr,
    // coalesced). LDS writes: lane-consecutive addresses, conflict-free.
    __shared__ float WT[E][1024];
#pragma unroll
    for (int k = 0; k < 4; ++k) {
        const int r = tid + 256 * k;
        const float4 w0 = ((const float4*)W)[r * 2];
        const float4 w1 = ((const float4*)W)[r * 2 + 1];
        WT[0][r] = w0.x; WT[1][r] = w0.y; WT[2][r] = w0.z; WT[3][r] = w0.w;
        WT[4][r] = w1.x; WT[5][r] = w1.y; WT[6][r] = w1.z; WT[7][r] = w1.w;
    }
    __syncthreads();

    // ---- 4 tokens per wave, 16 per block ----
    for (int it = 0; it < 4; ++it) {
        const int tk = blockIdx.x * 16 + wave * 4 + it;

        // part[c][e] replicates round-1 "wave c" partial: virtual thread
        // vt = c*64+lane handles d = vt*4 .. vt*4+4 with the same fmaf chain.
        float part[4][E];
#pragma unroll
        for (int c = 0; c < 4; ++c)
#pragma unroll
            for (int e = 0; e < E; ++e) part[c][e] = 0.0f;

#pragma unroll
        for (int c = 0; c < 4; ++c) {
            const float4 xv = ((const float4*)(x + (size_t)tk * D))[c * 64 + lane];
            const float xs[4] = {xv.x, xv.y, xv.z, xv.w};
            const int r0 = (c * 64 + lane) * 4;
#pragma unroll
            for (int e = 0; e < E; ++e) {
                const float4 wv = *(const float4*)(&WT[e][r0]);
                float a = part[c][e];
                a = fmaf(xs[0], wv.x, a);
                a = fmaf(xs[1], wv.y, a);
                a = fmaf(xs[2], wv.z, a);
                a = fmaf(xs[3], wv.w, a);
                part[c][e] = a;
            }
        }
        // same xor-butterfly order as round 1, per virtual wave c
#pragma unroll
        for (int off = 32; off > 0; off >>= 1) {
#pragma unroll
            for (int c = 0; c < 4; ++c)
#pragma unroll
                for (int e = 0; e < E; ++e)
                    part[c][e] += __shfl_xor(part[c][e], off, 64);
        }

        if (lane == 0) {
            const float c_scale = (float)(1.0 - 2e-7);
            const float c_shift = (float)(1e-7);

            float lg[E], lp[E], sc[E];
            float m = -INFINITY;
#pragma unroll
            for (int e = 0; e < E; ++e) {
                lg[e] = part[0][e] + part[1][e] + part[2][e] + part[3][e] + bvec[e];
                m = fmaxf(m, lg[e]);
            }
            float s = 0.0f;
            float ex[E];
#pragma unroll
            for (int e = 0; e < E; ++e) { ex[e] = expf(lg[e] - m); s += ex[e]; }
#pragma unroll
            for (int e = 0; e < E; ++e) {
                float p = ex[e] / s;
                lp[e]   = logf(p + GATE_EPS);
                float u = noise[(size_t)tk * E + e] * c_scale + c_shift;
                float g = -logf(-logf(u));
                sc[e]   = lp[e] + g;
            }
            int i1 = 0; float s1 = sc[0];
#pragma unroll
            for (int e = 1; e < E; ++e) if (sc[e] > s1) { s1 = sc[e]; i1 = e; }
            int i2 = -1; float s2 = -INFINITY;
#pragma unroll
            for (int e = 0; e < E; ++e)
                if (e != i1 && sc[e] > s2) { s2 = sc[e]; i2 = e; }

            idx_ws[tk] = make_int2(i1, i2);
            aux_ws[tk] = (rewards[tk] - baseline[0]) * (lp[i1] + lp[i2]);
        }
    }
}

__global__ __launch_bounds__(256) void rlgate_combine(
    const float* __restrict__ eo,       // [E, BT, D]
    const int2*  __restrict__ idx_ws,   // [BT]
    float* __restrict__ out,            // [BT, D]
    int BT, int D)
{
    const int bt  = blockIdx.x;
    const int tid = threadIdx.x;
    const int2 id = idx_ws[bt];   // uniform address -> broadcast
    const float4 a = ((const float4*)(eo + ((size_t)id.x * BT + bt) * (size_t)D))[tid];
    const float4 b = ((const float4*)(eo + ((size_t)id.y * BT + bt) * (size_t)D))[tid];
    float4 o;
    o.x = (a.x + b.x) * 0.5f;
    o.y = (a.y + b.y) * 0.5f;
    o.z = (a.z + b.z) * 0.5f;
    o.w = (a.w + b.w) * 0.5f;
    ((float4*)(out + (size_t)bt * (size_t)D))[tid] = o;
}

__global__ __launch_bounds__(256) void rlgate_aux_reduce(
    const float* __restrict__ aux_ws, float* __restrict__ out_aux, int BT)
{
    const int tid  = threadIdx.x;
    const int lane = tid & 63;
    const int wave = tid >> 6;
    float s = 0.0f;
    for (int i = tid; i < BT; i += 256) s += aux_ws[i];
#pragma unroll
    for (int off = 32; off > 0; off >>= 1) s += __shfl_xor(s, off, 64);
    __shared__ float red[4];
    if (lane == 0) red[wave] = s;
    __syncthreads();
    if (tid == 0)
        out_aux[0] = -(red[0] + red[1] + red[2] + red[3]) / (float)BT;
}

extern "C" void kernel_launch(void* const* d_in, const int* in_sizes, int n_in,
                              void* d_out, int out_size, void* d_ws, size_t ws_size,
                              hipStream_t stream)
{
    const float* x        = (const float*)d_in[0];
    const float* eo       = (const float*)d_in[1];
    const float* rewards  = (const float*)d_in[2];
    const float* W        = (const float*)d_in[3];
    const float* bvec     = (const float*)d_in[4];
    const float* baseline = (const float*)d_in[5];
    const float* noise    = (const float*)d_in[6];
    // d_in[7] = top_k (always 2; hardcoded)

    const int BT = in_sizes[2];              // 8192
    const int D  = in_sizes[0] / BT;         // 1024

    float* out    = (float*)d_out;
    float* outaux = out + (size_t)BT * D;
    float* aux_ws = (float*)d_ws;                    // [BT] floats
    int2*  idx_ws = (int2*)((char*)d_ws + (size_t)BT * sizeof(float));

    rlgate_gate<<<BT / 16, 256, 0, stream>>>(x, rewards, W, bvec, baseline,
                                             noise, idx_ws, aux_ws, BT, D);
    rlgate_combine<<<BT, D / 4, 0, stream>>>(eo, idx_ws, out, BT, D);
    rlgate_aux_reduce<<<1, 256, 0, stream>>>(aux_ws, outaux, BT);
}

// Round 3
// 376.044 us; speedup vs baseline: 1.0209x; 1.0209x over previous
//
#include <hip/hip_runtime.h>

// RLGate, round 3: single fused gate+combine kernel (one block per token)
// + tiny aux reduce. Round-1's fused structure was right; its defect was the
// per-thread W walk (32 scalar loads at 128B thread stride -> 64 cache lines
// per wave instr). Here W is staged coalesced into LDS transposed (like
// round 2), then each thread reads its 4 coefficients per expert as one
// ds_read_b128. W re-read per block is 8192 x 32KB = 256MB of L2 traffic
// (~8us at 34.5TB/s), overlapped with the ~128MB HBM stream.
//
// NUMERICS: logits bitwise-identical to rounds 1-2 (absmax 0.0): same fmaf
// chain per accumulator (xs[0..3] in order), same 64-lane xor butterfly
// (offsets 32..1, e inner), same red[0]+red[1]+red[2]+red[3]+b[e] order,
// same scalar softmax/Gumbel/top-2 -> selections cannot flip.

#define GATE_EPS 1e-9f

__global__ __launch_bounds__(256) void rlgate_fused(
    const float* __restrict__ x,        // [BT, D]
    const float* __restrict__ eo,       // [E, BT, D]
    const float* __restrict__ rewards,  // [BT]
    const float* __restrict__ W,        // [D, E]
    const float* __restrict__ bvec,     // [E]
    const float* __restrict__ baseline, // [1]
    const float* __restrict__ noise,    // [BT, E]
    float* __restrict__ out,            // [BT, D]
    float* __restrict__ aux_ws,         // [BT]
    int BT, int D)
{
    constexpr int E = 8;
    const int bt   = blockIdx.x;
    const int tid  = threadIdx.x;
    const int lane = tid & 63;
    const int wave = tid >> 6;

    // ---- stage W transposed into LDS: WT[e][d] = W[d][e] ----
    // thread t reads rows t, t+256, t+512, t+768: consecutive lanes read
    // consecutive 32B -> fully coalesced; LDS writes lane-consecutive
    // (2 lanes/bank aliasing = free on gfx950).
    __shared__ float WT[E][1024];
    __shared__ float red[4][E];
    __shared__ int   sh_idx[2];
#pragma unroll
    for (int k = 0; k < 4; ++k) {
        const int r = tid + 256 * k;
        const float4 w0 = ((const float4*)W)[r * 2];
        const float4 w1 = ((const float4*)W)[r * 2 + 1];
        WT[0][r] = w0.x; WT[1][r] = w0.y; WT[2][r] = w0.z; WT[3][r] = w0.w;
        WT[4][r] = w1.x; WT[5][r] = w1.y; WT[6][r] = w1.z; WT[7][r] = w1.w;
    }

    // x load can start before the barrier (independent of LDS)
    const float4 xv = ((const float4*)(x + (size_t)bt * D))[tid];
    const float xs[4] = {xv.x, xv.y, xv.z, xv.w};
    __syncthreads();

    // ---- gate logits: thread covers d = tid*4 .. tid*4+3 ----
    float part[E];
#pragma unroll
    for (int e = 0; e < E; ++e) part[e] = 0.0f;
    const int r0 = tid * 4;
#pragma unroll
    for (int e = 0; e < E; ++e) {
        const float4 wv = *(const float4*)(&WT[e][r0]);
        float a = part[e];
        a = fmaf(xs[0], wv.x, a);
        a = fmaf(xs[1], wv.y, a);
        a = fmaf(xs[2], wv.z, a);
        a = fmaf(xs[3], wv.w, a);
        part[e] = a;
    }
#pragma unroll
    for (int off = 32; off > 0; off >>= 1) {
#pragma unroll
        for (int e = 0; e < E; ++e)
            part[e] += __shfl_xor(part[e], off, 64);
    }
    if (lane == 0) {
#pragma unroll
        for (int e = 0; e < E; ++e) red[wave][e] = part[e];
    }
    __syncthreads();

    if (tid == 0) {
        const float c_scale = (float)(1.0 - 2e-7);
        const float c_shift = (float)(1e-7);

        float lg[E], lp[E], sc[E];
        float m = -INFINITY;
#pragma unroll
        for (int e = 0; e < E; ++e) {
            lg[e] = red[0][e] + red[1][e] + red[2][e] + red[3][e] + bvec[e];
            m = fmaxf(m, lg[e]);
        }
        float s = 0.0f;
        float ex[E];
#pragma unroll
        for (int e = 0; e < E; ++e) { ex[e] = expf(lg[e] - m); s += ex[e]; }
#pragma unroll
        for (int e = 0; e < E; ++e) {
            float p = ex[e] / s;
            lp[e]   = logf(p + GATE_EPS);
            float u = noise[(size_t)bt * E + e] * c_scale + c_shift;
            float g = -logf(-logf(u));
            sc[e]   = lp[e] + g;
        }
        int i1 = 0; float s1 = sc[0];
#pragma unroll
        for (int e = 1; e < E; ++e) if (sc[e] > s1) { s1 = sc[e]; i1 = e; }
        int i2 = -1; float s2 = -INFINITY;
#pragma unroll
        for (int e = 0; e < E; ++e)
            if (e != i1 && sc[e] > s2) { s2 = sc[e]; i2 = e; }

        sh_idx[0] = i1;
        sh_idx[1] = i2;
        aux_ws[bt] = (rewards[bt] - baseline[0]) * (lp[i1] + lp[i2]);
    }
    __syncthreads();

    // ---- combine: average the two selected expert rows ----
    const size_t b1 = ((size_t)sh_idx[0] * BT + bt) * (size_t)D;
    const size_t b2 = ((size_t)sh_idx[1] * BT + bt) * (size_t)D;
    const float4 a = ((const float4*)(eo + b1))[tid];
    const float4 c = ((const float4*)(eo + b2))[tid];
    float4 o;
    o.x = (a.x + c.x) * 0.5f;
    o.y = (a.y + c.y) * 0.5f;
    o.z = (a.z + c.z) * 0.5f;
    o.w = (a.w + c.w) * 0.5f;
    ((float4*)(out + (size_t)bt * D))[tid] = o;
}

__global__ __launch_bounds__(256) void rlgate_aux_reduce(
    const float* __restrict__ aux_ws, float* __restrict__ out_aux, int BT)
{
    const int tid  = threadIdx.x;
    const int lane = tid & 63;
    const int wave = tid >> 6;
    float s = 0.0f;
    for (int i = tid; i < BT; i += 256) s += aux_ws[i];
#pragma unroll
    for (int off = 32; off > 0; off >>= 1) s += __shfl_xor(s, off, 64);
    __shared__ float red[4];
    if (lane == 0) red[wave] = s;
    __syncthreads();
    if (tid == 0)
        out_aux[0] = -(red[0] + red[1] + red[2] + red[3]) / (float)BT;
}

extern "C" void kernel_launch(void* const* d_in, const int* in_sizes, int n_in,
                              void* d_out, int out_size, void* d_ws, size_t ws_size,
                              hipStream_t stream)
{
    const float* x        = (const float*)d_in[0];
    const float* eo       = (const float*)d_in[1];
    const float* rewards  = (const float*)d_in[2];
    const float* W        = (const float*)d_in[3];
    const float* bvec     = (const float*)d_in[4];
    const float* baseline = (const float*)d_in[5];
    const float* noise    = (const float*)d_in[6];
    // d_in[7] = top_k (always 2; hardcoded)

    const int BT = in_sizes[2];              // 8192
    const int D  = in_sizes[0] / BT;         // 1024

    float* out    = (float*)d_out;
    float* outaux = out + (size_t)BT * D;
    float* aux_ws = (float*)d_ws;            // [BT]

    rlgate_fused<<<BT, D / 4, 0, stream>>>(x, eo, rewards, W, bvec, baseline,
                                           noise, out, aux_ws, BT, D);
    rlgate_aux_reduce<<<1, 256, 0, stream>>>(aux_ws, outaux, BT);
}